// Round 13
// baseline (478.277 us; speedup 1.0000x reference)
//
#include <hip/hip_runtime.h>

#define L 2048
#define WIN 32   // match-scan window per round (R ~ 15 + Dmax/WIN; per-round union cost ~ WIN*130cy)

// ---------------------------------------------------------------------------
// k1: pairs[i] = BASES[argmax_b feat[0, b, i, 0]]   (first-max tie break)
// ---------------------------------------------------------------------------
__global__ void pairs_kernel(const float* __restrict__ feat, float* __restrict__ pairs) {
    int i = blockIdx.x * blockDim.x + threadIdx.x;
    if (i >= L) return;
    float best = feat[(size_t)i * L];
    int bi = 0;
#pragma unroll
    for (int b = 1; b < 4; ++b) {
        float v = feat[(size_t)b * L * L + (size_t)i * L];
        if (v > best) { best = v; bi = b; }
    }
    const float BV[4] = {2.0f, 3.0f, 5.0f, 7.0f};
    pairs[i] = BV[bi];
}

// ---------------------------------------------------------------------------
// k1b: pure tiled transpose  tr[i][j] = con[j][i]  (64x64 LDS tile, +1 pad).
// Coalesced read AND write; replaces build's 16x-overfetch column gather.
// ---------------------------------------------------------------------------
__global__ __launch_bounds__(256) void transpose_kernel(const float* __restrict__ con,
                                                        float* __restrict__ tr) {
    __shared__ float tile[64][65];
    const int bi = blockIdx.x, bj = blockIdx.y;    // output tile: rows 64*bi.., cols 64*bj..
    const int tid = threadIdx.x;
    const int c = tid & 63, r4 = tid >> 6;
#pragma unroll
    for (int rr = r4; rr < 64; rr += 4)            // stage con rows [64bj..], cols [64bi..]
        tile[rr][c] = con[(size_t)(bj * 64 + rr) * L + bi * 64 + c];
    __syncthreads();
#pragma unroll
    for (int rr = r4; rr < 64; rr += 4)            // tr[i][j] = tile[j-part][i-part]
        tr[(size_t)(bi * 64 + rr) * L + bj * 64 + c] = tile[c][rr];
}

// ---------------------------------------------------------------------------
// k2: one block per row i (XCD-swizzled) — round-2 verbatim except the
// symmetrize partner read: coalesced tr row when use_tr, else column gather.
// ---------------------------------------------------------------------------
__global__ __launch_bounds__(256) void build_kernel(const float* __restrict__ con,
                                                    const float* __restrict__ tr,
                                                    int use_tr,
                                                    const float* __restrict__ pairs,
                                                    unsigned short* __restrict__ lists,
                                                    int* __restrict__ cnt,
                                                    float* __restrict__ out) {
    __shared__ unsigned long long keys[L];
    __shared__ int lcnt;
    const int bid = blockIdx.x;
    const int i = (bid & 7) * 256 + (bid >> 3);   // XCD-bijective swizzle (2048 = 8*256)
    const int tid = threadIdx.x;
    if (tid == 0) lcnt = 0;
    __syncthreads();
    const float pi = pairs[i];
#pragma unroll
    for (int k = 0; k < L / 256; ++k) {
        int j = tid + k * 256;
        float a = con[(size_t)i * L + j];          // coalesced row read
        float b = use_tr ? tr[(size_t)i * L + j]   // coalesced transposed row
                         : con[(size_t)j * L + i]; // fallback gather
        out[(size_t)i * L + j] = 0.0f;             // pre-zero output row
        float v = 0.5f * (a + b);
        int d = i > j ? i - j : j - i;
        float pm = pi * pairs[j];
        bool valid = (d >= 4) && (pm == 14.0f || pm == 15.0f || pm == 35.0f) && (v > 0.0f);
        if (valid) {
            int pos = atomicAdd(&lcnt, 1);
            unsigned int vb = __float_as_uint(v);              // positive: bit order == value order
            unsigned int mn = (unsigned)(i < j ? i : j);
            unsigned int mx = (unsigned)(i < j ? j : i);
            unsigned int ef = mn * (unsigned)L + mx;           // < 2^22
            keys[pos] = ((unsigned long long)vb << 32) |
                        (unsigned long long)(0xFFFFFFFFu - ef); // value desc, then ef asc
        }
    }
    __syncthreads();
    const int c = lcnt;
    int Np = 1;
    while (Np < c) Np <<= 1;
    if (Np < 2) Np = 2;
    for (int t = c + tid; t < Np; t += 256) keys[t] = 0ull;
    __syncthreads();
    // bitonic sort, descending
    for (int k = 2; k <= Np; k <<= 1) {
        for (int s = k >> 1; s > 0; s >>= 1) {
            for (int x = tid; x < Np; x += 256) {
                int l = x ^ s;
                if (l > x) {
                    unsigned long long a = keys[x], b = keys[l];
                    bool up = ((x & k) == 0);
                    if (up ? (a < b) : (a > b)) { keys[x] = b; keys[l] = a; }
                }
            }
            __syncthreads();
        }
    }
    for (int t = tid; t < c; t += 256) {
        unsigned int ef = 0xFFFFFFFFu - (unsigned int)(keys[t] & 0xFFFFFFFFull);
        unsigned int mn = ef >> 11;          // /L
        unsigned int mx = ef & (L - 1);      // %L
        lists[(size_t)i * L + t] = (unsigned short)((mn == (unsigned)i) ? mx : mn);
    }
    if (tid == 0) cnt[i] = c;
}

// ---------------------------------------------------------------------------
// k3: mutual-best matching == sequential greedy. 1024 threads, 2 rows/thread.
// Round-12 PASSING kernel, single constant changed: window 8 -> WIN(32).
// Serial scan body kept (flat-batched LDS scans failed nondeterministically).
// ---------------------------------------------------------------------------
__global__ __launch_bounds__(1024) void match_kernel(const float* __restrict__ con,
                                                     const unsigned short* __restrict__ lists,
                                                     const int* __restrict__ cnt,
                                                     float* __restrict__ out) {
    __shared__ short memo[L];
    __shared__ short bestj[L];
    __shared__ unsigned int matched[1024];
    __shared__ int nm;
    __shared__ int ch[2];
    __shared__ int pg[2];
    const int tid = threadIdx.x;
    const int r0 = tid, r1 = tid + 1024;
    memo[r0] = 0; memo[r1] = 0;
    if (tid == 0) { nm = 0; ch[0] = 0; ch[1] = 0; pg[0] = 0; pg[1] = 0; }
    int p0 = 0, p1 = 0;
    const int c0 = cnt[r0], c1 = cnt[r1];
    const uint4* row0 = reinterpret_cast<const uint4*>(lists + (size_t)r0 * L);
    const uint4* row1 = reinterpret_cast<const uint4*>(lists + (size_t)r1 * L);
    uint4 buf0, buf1;
    int cb0 = -1, cb1 = -1;
    int ph = 0;
    __syncthreads();
    while (true) {
        // ---- phase 1: each free row scans ≤WIN entries toward its first free ----
        int b0 = -1, b1 = -1;
        if (!memo[r0]) {
            int wend0 = (p0 + WIN < c0) ? p0 + WIN : c0;
            while (p0 < wend0) {
                int nc = p0 >> 3;
                if (nc != cb0) { buf0 = row0[nc]; cb0 = nc; }
                int sl = p0 & 7;
                unsigned w = (sl < 4) ? ((sl < 2) ? buf0.x : buf0.y)
                                      : ((sl < 6) ? buf0.z : buf0.w);
                int cand = (int)((w >> ((sl & 1) * 16)) & 0xFFFFu);
                if (!memo[cand]) { b0 = cand; break; }
                ++p0;
            }
            if (b0 < 0 && p0 < c0) pg[ph] = 1;   // mid-scan: advanced, not done
        }
        if (!memo[r1]) {
            int wend1 = (p1 + WIN < c1) ? p1 + WIN : c1;
            while (p1 < wend1) {
                int nc = p1 >> 3;
                if (nc != cb1) { buf1 = row1[nc]; cb1 = nc; }
                int sl = p1 & 7;
                unsigned w = (sl < 4) ? ((sl < 2) ? buf1.x : buf1.y)
                                      : ((sl < 6) ? buf1.z : buf1.w);
                int cand = (int)((w >> ((sl & 1) * 16)) & 0xFFFFu);
                if (!memo[cand]) { b1 = cand; break; }
                ++p1;
            }
            if (b1 < 0 && p1 < c1) pg[ph] = 1;
        }
        bestj[r0] = (short)b0;          // unconditional, every row, every round
        bestj[r1] = (short)b1;
        __syncthreads();            // A: proposals visible
        // ---- phase 2: mutual proposals become matches (record only) ----
        if (b0 >= 0 && r0 < b0 && bestj[b0] == (short)r0) {
            memo[r0] = 1; memo[b0] = 1;
            matched[atomicAdd(&nm, 1)] = ((unsigned)r0 << 16) | (unsigned)p0;
            ch[ph] = 1;
        }
        if (b1 >= 0 && r1 < b1 && bestj[b1] == (short)r1) {
            memo[r1] = 1; memo[b1] = 1;
            matched[atomicAdd(&nm, 1)] = ((unsigned)r1 << 16) | (unsigned)p1;
            ch[ph] = 1;
        }
        if (tid == 0) { ch[ph ^ 1] = 0; pg[ph ^ 1] = 0; }   // prep next round's flags
        __syncthreads();            // B: memo/matched/flags visible
        if (ch[ph] == 0 && pg[ph] == 0) break;   // uniform exit: no match, no progress
        ph ^= 1;
    }
    __syncthreads();
    // ---- deferred emission: con gathers + out scatters off the round path ----
    const int m = nm;
    for (int t = tid; t < m; t += 1024) {
        unsigned mp = matched[t];
        int r = (int)(mp >> 16);
        int p = (int)(mp & 0xFFFFu);
        int b = (int)lists[(size_t)r * L + p];
        float v = 0.5f * (con[(size_t)r * L + b] + con[(size_t)b * L + r]);
        out[(size_t)r * L + b] = v;
        out[(size_t)b * L + r] = v;
    }
}

extern "C" void kernel_launch(void* const* d_in, const int* in_sizes, int n_in,
                              void* d_out, int out_size, void* d_ws, size_t ws_size,
                              hipStream_t stream) {
    const float* con  = (const float*)d_in[0];
    const float* feat = (const float*)d_in[1];
    float* out = (float*)d_out;
    char* ws = (char*)d_ws;
    unsigned short* lists = (unsigned short*)ws;                         // 8 MB
    size_t off = (size_t)L * L * sizeof(unsigned short);
    int*   cnt   = (int*)(ws + off);   off += L * sizeof(int);           // 8 KB
    float* pairs = (float*)(ws + off); off += L * sizeof(float);         // 8 KB
    float* tr    = (float*)(ws + off); off += (size_t)L * L * sizeof(float); // 16 MB
    const int use_tr = (ws_size >= off) ? 1 : 0;

    pairs_kernel<<<(L + 255) / 256, 256, 0, stream>>>(feat, pairs);
    if (use_tr)
        transpose_kernel<<<dim3(32, 32), 256, 0, stream>>>(con, tr);
    build_kernel<<<L, 256, 0, stream>>>(con, tr, use_tr, pairs, lists, cnt, out);
    match_kernel<<<1, 1024, 0, stream>>>(con, lists, cnt, out);
}